// Round 4
// baseline (6152.016 us; speedup 1.0000x reference)
//
#include <hip/hip_runtime.h>

#define T_STEPS 2048
#define BATCH   2048
#define HIDN    128

typedef short v8s __attribute__((ext_vector_type(8)));
typedef float v4f __attribute__((ext_vector_type(4)));
typedef unsigned short u16;
typedef unsigned int   u32;

// ---------------- LDS layout (bytes) ----------------
// W1 kt3 image: 32 tiles x 1KB b-frag chunks   [0, 32768)
// WX image:     32 tiles x 1KB                 [32768, 65536)
// WLIN image:   4 kt x 1KB                     [65536, 69632)
// h1 dbuf: 2 x 4KB fragment-order images       [69632, 77824)
// h2 dbuf: 2 x 4KB fragment-order images       [77824, 86016)
#define LDS_W1K3  0
#define LDS_WX    32768
#define LDS_WLIN  65536
#define LDS_H1    69632
#define LDS_H2    77824
#define LDS_TOTAL 86016

__device__ __forceinline__ u16 f2bf(float x) {
    u32 u = __float_as_uint(x);
    u32 r = (u + 0x7FFFu + ((u >> 16) & 1u)) >> 16;
    return (u16)r;
}
__device__ __forceinline__ float rcpf(float x) { return __builtin_amdgcn_rcpf(x); }
__device__ __forceinline__ float sigf(float x) { return rcpf(1.0f + __expf(-x)); }
__device__ __forceinline__ float tanhf_(float x) {
    float e = __expf(2.0f * x);
    return 1.0f - 2.0f * rcpf(e + 1.0f);
}
// byte offset of element (row r, k) inside a 4KB fragment-order A image
__device__ __forceinline__ int fragoff(int r, int k) {
    return ((k >> 5) << 10) + ((((k >> 3) & 3) * 16 + r) << 4) + ((k & 7) << 1);
}

__global__ __launch_bounds__(512, 2) void lstm_seq_kernel(
    const float* __restrict__ input,
    const float* __restrict__ W_ih1, const float* __restrict__ W_hh1,
    const float* __restrict__ b_ih1, const float* __restrict__ b_hh1,
    const float* __restrict__ W_ih2, const float* __restrict__ W_hh2,
    const float* __restrict__ b_ih2, const float* __restrict__ b_hh2,
    const float* __restrict__ W_lin, const float* __restrict__ b_lin,
    const float* __restrict__ h0,  const float* __restrict__ c0,
    const float* __restrict__ h02, const float* __restrict__ c02,
    float* __restrict__ out)
{
    extern __shared__ char smem[];
    const int tid = threadIdx.x;
    const int w   = tid >> 6;     // wave 0..7
    const int l   = tid & 63;
    const int u   = l & 15;       // MFMA row/col index
    const int q   = l >> 4;       // MFMA quad
    const int b0  = blockIdx.x * 8;
    const bool low = (q < 2);     // q<2: layer-2 cells; q>=2: layer-1 cells
    const int j   = w * 16 + u;   // hidden unit owned by this lane

    // ---------------- init: zero h bufs (16KB) ----------------
    for (int e = tid; e < 4096; e += 512)
        ((float*)(smem + LDS_H1))[e] = 0.0f;
    __syncthreads();
    // preload h0 -> h1buf[1] (rows m and m+8), h02 -> h2buf[1] (rows m)
    for (int e = tid; e < 1024; e += 512) {
        int m = e >> 7, jj = e & 127;
        u16 hv1 = f2bf(h0 [(b0 + m) * HIDN + jj]);
        u16 hv2 = f2bf(h02[(b0 + m) * HIDN + jj]);
        int fo = fragoff(m, jj);
        *(u16*)(smem + LDS_H1 + 4096 + fo)       = hv1;
        *(u16*)(smem + LDS_H1 + 4096 + fo + 128) = hv1;   // row m+8 dup
        *(u16*)(smem + LDS_H2 + 4096 + fo)       = hv2;
    }

    // ---------------- W1 kt3 image + WX image in LDS ----------------
    // col permutation: c_local = gate*16 + u  ->  original row r = gate*128 + j
    #pragma unroll
    for (int tl = 0; tl < 4; ++tl) {
        int r = tl * 128 + j;
        {   // kt = 3 chunk of W_hh1
            const float* src = W_hh1 + r * HIDN + 3 * 32 + q * 8;
            v8s f;
            #pragma unroll
            for (int b = 0; b < 8; ++b) f[b] = (short)f2bf(src[b]);
            *(v8s*)(smem + LDS_W1K3 + ((w * 4 + tl) << 10) + l * 16) = f;
        }
        {   // x-tile weights (K slots 0..3 of a 32-wide tile)
            v8s f;
            #pragma unroll
            for (int b = 0; b < 8; ++b) {
                int k = q * 8 + b;
                f[b] = (k < 4) ? (short)f2bf(W_ih1[r * 4 + k]) : (short)0;
            }
            *(v8s*)(smem + LDS_WX + ((w * 4 + tl) << 10) + l * 16) = f;
        }
    }
    // W_lin b-frag image (wave 7; cols u<4 valid)
    if (w == 7) {
        #pragma unroll
        for (int kt = 0; kt < 4; ++kt) {
            v8s f;
            #pragma unroll
            for (int b = 0; b < 8; ++b) {
                int kk = kt * 32 + q * 8 + b;
                f[b] = (u < 4) ? (short)f2bf(W_lin[u * HIDN + kk]) : (short)0;
            }
            *(v8s*)(smem + LDS_WLIN + (kt << 10) + l * 16) = f;
        }
    }

    // ---------------- resident register fragments ----------------
    // layer-2 weights: kt 0..3 = W_ih2 (A=h1), kt 4..7 = W_hh2 (A=h2)
    v8s w2[4][8];
    #pragma unroll
    for (int tl = 0; tl < 4; ++tl) {
        int r = tl * 128 + j;
        #pragma unroll
        for (int kt = 0; kt < 8; ++kt) {
            const float* src = (kt < 4) ? (W_ih2 + r * HIDN + kt * 32 + q * 8)
                                        : (W_hh2 + r * HIDN + (kt - 4) * 32 + q * 8);
            v8s f;
            #pragma unroll
            for (int b = 0; b < 8; ++b) f[b] = (short)f2bf(src[b]);
            w2[tl][kt] = f;
        }
    }
    // layer-1 W_hh1 kt 0..2 resident (kt 3 streamed from LDS)
    v8s w1r[4][3];
    #pragma unroll
    for (int tl = 0; tl < 4; ++tl) {
        int r = tl * 128 + j;
        #pragma unroll
        for (int kt = 0; kt < 3; ++kt) {
            const float* src = W_hh1 + r * HIDN + kt * 32 + q * 8;
            v8s f;
            #pragma unroll
            for (int b = 0; b < 8; ++b) f[b] = (short)f2bf(src[b]);
            w1r[tl][kt] = f;
        }
    }

    // biases + c-state, selected per lane half
    float bg[4];
    #pragma unroll
    for (int g = 0; g < 4; ++g)
        bg[g] = low ? (b_ih2[g * 128 + j] + b_hh2[g * 128 + j])
                    : (b_ih1[g * 128 + j] + b_hh1[g * 128 + j]);
    float blin = (w == 7 && u < 4) ? b_lin[u] : 0.0f;
    float c[4];
    #pragma unroll
    for (int d = 0; d < 4; ++d) {
        int m = low ? (4 * q + d) : (4 * (q - 2) + d);
        c[d] = low ? c02[(b0 + m) * HIDN + j] : c0[(b0 + m) * HIDN + j];
    }
    // x[0] preload (lanes q==0, u>=8 hold batch row u-8)
    float4 xcur = {0, 0, 0, 0}, xnext = {0, 0, 0, 0};
    if (q == 0 && u >= 8)
        xcur = *(const float4*)(input + (long)(b0 + u - 8) * 4);

    __syncthreads();

    // ---------------- pipelined time loop: slot s = l1(s) + l2(s-1) -------
    for (int s = 0; s <= T_STEPS; ++s) {
        const char* h1r = smem + LDS_H1 + ((s - 1) & 1) * 4096;  // h1[s-1]
        const char* h2r = smem + LDS_H2 + (s & 1) * 4096;        // h2[s-2]
        const bool doL1 = (s < T_STEPS);
        const bool doL2 = (s >= 1);

        if (q == 0 && u >= 8 && s + 1 < T_STEPS)
            xnext = *(const float4*)(input + ((long)(s + 1) * BATCH + b0 + u - 8) * 4);

        v4f acc1[4] = {{0,0,0,0},{0,0,0,0},{0,0,0,0},{0,0,0,0}};
        v4f acc2[4] = {{0,0,0,0},{0,0,0,0},{0,0,0,0},{0,0,0,0}};

        // ---- K-half 1: A = h1[s-1] feeds layer-2 (W_ih2) and layer-1 (W_hh1)
        // per-kt frag rotation: one A frag live at a time
        #pragma unroll
        for (int kt = 0; kt < 4; ++kt) {
            v8s a1k = *(const v8s*)(h1r + (kt << 10) + l * 16);
            if (doL2) {
                #pragma unroll
                for (int tl = 0; tl < 4; ++tl)
                    acc2[tl] = __builtin_amdgcn_mfma_f32_16x16x32_bf16(a1k, w2[tl][kt], acc2[tl], 0, 0, 0);
            }
            if (doL1) {
                if (kt < 3) {
                    #pragma unroll
                    for (int tl = 0; tl < 4; ++tl)
                        acc1[tl] = __builtin_amdgcn_mfma_f32_16x16x32_bf16(a1k, w1r[tl][kt], acc1[tl], 0, 0, 0);
                } else {
                    #pragma unroll
                    for (int tl = 0; tl < 4; ++tl) {
                        v8s wf = *(const v8s*)(smem + LDS_W1K3 + ((w * 4 + tl) << 10) + l * 16);
                        acc1[tl] = __builtin_amdgcn_mfma_f32_16x16x32_bf16(a1k, wf, acc1[tl], 0, 0, 0);
                    }
                }
            }
        }

        // ---- K-half 2: A = h2[s-2] feeds layer-2 (W_hh2) + wave-7 out tile
        v4f oa = {0.f, 0.f, 0.f, 0.f};
        if (doL2) {
            #pragma unroll
            for (int kt = 0; kt < 4; ++kt) {
                v8s a2k = *(const v8s*)(h2r + (kt << 10) + l * 16);
                #pragma unroll
                for (int tl = 0; tl < 4; ++tl)
                    acc2[tl] = __builtin_amdgcn_mfma_f32_16x16x32_bf16(a2k, w2[tl][kt + 4], acc2[tl], 0, 0, 0);
                if (w == 7) {
                    v8s wl = *(const v8s*)(smem + LDS_WLIN + (kt << 10) + l * 16);
                    oa = __builtin_amdgcn_mfma_f32_16x16x32_bf16(a2k, wl, oa, 0, 0, 0);
                }
            }
            if (w == 7 && s >= 2 && low && u < 4) {
                #pragma unroll
                for (int d = 0; d < 4; ++d)
                    out[((long)(s - 2) * BATCH + b0 + 4 * q + d) * 4 + u] = oa[d] + blin;
            }
        }

        // ---- layer-2 activation (q<2 lanes) — acc2 complete, do it now ----
        if (low && doL2) {
            char* hw = (char*)smem + LDS_H2 + ((s - 1) & 1) * 4096;
            #pragma unroll
            for (int d = 0; d < 4; ++d) {
                float gI = acc2[0][d] + bg[0];
                float gF = acc2[1][d] + bg[1];
                float gG = acc2[2][d] + bg[2];
                float gO = acc2[3][d] + bg[3];
                float si = sigf(gI), sf = sigf(gF), tg = tanhf_(gG), so = sigf(gO);
                c[d] = sf * c[d] + si * tg;
                u16 hb = f2bf(so * tanhf_(c[d]));
                int r = 4 * q + d;
                *(u16*)(hw + fragoff(r, j)) = hb;
            }
        }

        // ---- x tile completes layer-1 ----
        if (doL1) {
            v8s ax = {0, 0, 0, 0, 0, 0, 0, 0};
            if (q == 0 && u >= 8) {
                ax[0] = (short)f2bf(xcur.x); ax[1] = (short)f2bf(xcur.y);
                ax[2] = (short)f2bf(xcur.z); ax[3] = (short)f2bf(xcur.w);
            }
            #pragma unroll
            for (int tl = 0; tl < 4; ++tl) {
                v8s wxf = *(const v8s*)(smem + LDS_WX + ((w * 4 + tl) << 10) + l * 16);
                acc1[tl] = __builtin_amdgcn_mfma_f32_16x16x32_bf16(ax, wxf, acc1[tl], 0, 0, 0);
            }
        }

        // ---- layer-1 activation (q>=2 lanes) ----
        if (!low && doL1) {
            char* hw = (char*)smem + LDS_H1 + (s & 1) * 4096;
            #pragma unroll
            for (int d = 0; d < 4; ++d) {
                float gI = acc1[0][d] + bg[0];
                float gF = acc1[1][d] + bg[1];
                float gG = acc1[2][d] + bg[2];
                float gO = acc1[3][d] + bg[3];
                float si = sigf(gI), sf = sigf(gF), tg = tanhf_(gG), so = sigf(gO);
                c[d] = sf * c[d] + si * tg;
                u16 hb = f2bf(so * tanhf_(c[d]));
                int r = 4 * (q - 2) + d;
                *(u16*)(hw + fragoff(r, j))     = hb;
                *(u16*)(hw + fragoff(r + 8, j)) = hb;   // dup row for row-shift trick
            }
        }

        xcur = xnext;
        __syncthreads();
    }

    // epilogue: out[T-1] from h2[T-1]
    if (w == 7) {
        const char* h2r = smem + LDS_H2 + ((T_STEPS - 1) & 1) * 4096;
        v4f oa = {0.f, 0.f, 0.f, 0.f};
        #pragma unroll
        for (int kt = 0; kt < 4; ++kt) {
            v8s a2k = *(const v8s*)(h2r + (kt << 10) + l * 16);
            v8s wl  = *(const v8s*)(smem + LDS_WLIN + (kt << 10) + l * 16);
            oa = __builtin_amdgcn_mfma_f32_16x16x32_bf16(a2k, wl, oa, 0, 0, 0);
        }
        if (low && u < 4) {
            #pragma unroll
            for (int d = 0; d < 4; ++d)
                out[((long)(T_STEPS - 1) * BATCH + b0 + 4 * q + d) * 4 + u] = oa[d] + blin;
        }
    }
}

extern "C" void kernel_launch(void* const* d_in, const int* in_sizes, int n_in,
                              void* d_out, int out_size, void* d_ws, size_t ws_size,
                              hipStream_t stream) {
    const float* input = (const float*)d_in[0];
    // d_in[1] = future (unused, ==0)
    const float* W_ih1 = (const float*)d_in[2];
    const float* W_hh1 = (const float*)d_in[3];
    const float* b_ih1 = (const float*)d_in[4];
    const float* b_hh1 = (const float*)d_in[5];
    const float* W_ih2 = (const float*)d_in[6];
    const float* W_hh2 = (const float*)d_in[7];
    const float* b_ih2 = (const float*)d_in[8];
    const float* b_hh2 = (const float*)d_in[9];
    const float* W_lin = (const float*)d_in[10];
    const float* b_lin = (const float*)d_in[11];
    const float* h0    = (const float*)d_in[12];
    const float* c0    = (const float*)d_in[13];
    const float* h02   = (const float*)d_in[14];
    const float* c02   = (const float*)d_in[15];
    float* out = (float*)d_out;

    (void)hipFuncSetAttribute((const void*)lstm_seq_kernel,
                              hipFuncAttributeMaxDynamicSharedMemorySize, LDS_TOTAL);
    lstm_seq_kernel<<<BATCH / 8, 512, LDS_TOTAL, stream>>>(
        input, W_ih1, W_hh1, b_ih1, b_hh1, W_ih2, W_hh2, b_ih2, b_hh2,
        W_lin, b_lin, h0, c0, h02, c02, out);
}